// Round 17
// baseline (111.357 us; speedup 1.0000x reference)
//
#include <hip/hip_runtime.h>
#include <math.h>
#include <limits.h>

#define NQ    64
#define NE    10000
#define K     10
#define NBLK  500         // K1 blocks; 20 entities each (500*20 = 10000)
#define EPB   20
#define TPB   512         // 8 waves = 2 entity-slots x 4 dim-quarters
#define EPS   10          // entities per slot-wave
#define SLOT  11          // padded merge-slot stride

// ---------- comparator (lax.top_k: ties -> lower index first) ----------
// BOT lists store NEGATED values, so this single comparator serves both directions.
__device__ __forceinline__ bool better_top(double v, int i, double v2, int i2) {
    return (v > v2) || (v == v2 && i < i2);
}

// merge two sorted K-lists in LDS (u16 indices; slot stride SLOT) -> into A
__device__ __forceinline__ void merge_slots16(double* Mv, unsigned short* Mi, int A, int B) {
    double ov[K]; unsigned short oi[K];
    int a = 0, b = 0;
#pragma unroll
    for (int o = 0; o < K; ++o) {
        double va = Mv[A * SLOT + a]; int ia = Mi[A * SLOT + a];
        double vb = Mv[B * SLOT + b]; int ib = Mi[B * SLOT + b];
        bool pick = better_top(va, ia, vb, ib);
        ov[o] = pick ? va : vb;
        oi[o] = (unsigned short)(pick ? ia : ib);
        if (pick) ++a; else ++b;
    }
#pragma unroll
    for (int o = 0; o < K; ++o) { Mv[A * SLOT + o] = ov[o]; Mi[A * SLOT + o] = oi[o]; }
}

// ---------------- kernel 0: exact f64 entity row sums (wave per row) ----------------
__global__ __launch_bounds__(256) void ent_sums(const float* __restrict__ E,
                                                double* __restrict__ Se) {
    const int w = threadIdx.x >> 6, l = threadIdx.x & 63;
    const int j = blockIdx.x * 4 + w;          // 2500 blocks * 4 waves = 10000 rows
    float4 v = reinterpret_cast<const float4*>(E)[(size_t)j * 64 + l];
    double s = ((double)v.x + (double)v.y) + ((double)v.z + (double)v.w);
#pragma unroll
    for (int m = 1; m < 64; m <<= 1) s += __shfl_xor(s, m, 64);
    if (l == 0) Se[j] = s;   // exact: 31-bit value in f64
}

// 16-dim batch: mins are exact; pair sums exact in f32 (24-bit); f64 accum exact
#define DIMS16(B)                                                           \
    {                                                                       \
        float4 e0 = ep[(B) * 4 + 0], e1 = ep[(B) * 4 + 1];                  \
        float4 e2 = ep[(B) * 4 + 2], e3 = ep[(B) * 4 + 3];                  \
        float4 q0 = qreg[(B) * 4 + 0], q1 = qreg[(B) * 4 + 1];              \
        float4 q2 = qreg[(B) * 4 + 2], q3 = qreg[(B) * 4 + 3];              \
        float p0 = fminf(q0.x, e0.x) + fminf(q0.y, e0.y);                   \
        float p1 = fminf(q0.z, e0.z) + fminf(q0.w, e0.w);                   \
        float p2 = fminf(q1.x, e1.x) + fminf(q1.y, e1.y);                   \
        float p3 = fminf(q1.z, e1.z) + fminf(q1.w, e1.w);                   \
        float p4 = fminf(q2.x, e2.x) + fminf(q2.y, e2.y);                   \
        float p5 = fminf(q2.z, e2.z) + fminf(q2.w, e2.w);                   \
        float p6 = fminf(q3.x, e3.x) + fminf(q3.y, e3.y);                   \
        float p7 = fminf(q3.z, e3.z) + fminf(q3.w, e3.w);                   \
        acc0 += (double)p0 + (double)p2;                                    \
        acc1 += (double)p1 + (double)p3;                                    \
        acc0 += (double)p4 + (double)p6;                                    \
        acc1 += (double)p5 + (double)p7;                                    \
    }

// ---------------- kernel 1: Q in VGPRs, entity via uniform loads ----------------
// 500 blocks x 512 thr. Wave w: slot s = w>>2 (entities b*20+s*10..+10),
// quarter qr = w&3 (dims qr*64..+64). Lane l = query l (all 64).
// Inner loop is PURE REGISTER: qreg static-unrolled, entity float4 at
// wave-uniform address (one load serves all 64 queries). No LDS/readlane per dim.
// LDS (static 66560B -> 2 blocks/CU):
//   P1 QT float4[64*65] (transposed Q for reg-fill)
//   P2 overlay: SQd f64[4][64] @0 (2048) | Cd f64[2][10][4][64] @2048 (40960)
//   P3 overlay: Mv f64[128*SLOT] @0 (11264) | Mi u16[128*SLOT] @11264 (2816)
__global__ __launch_bounds__(TPB, 2) void jac_part(
        const float* __restrict__ Q, const float* __restrict__ E,
        const double* __restrict__ Se,
        double* __restrict__ pvT, double* __restrict__ pvB,
        unsigned short* __restrict__ piT, unsigned short* __restrict__ piB) {
    __shared__ float4 SMraw[64 * 65];   // 66560 B
    char* SM = (char*)SMraw;
    float4* QT = SMraw;

    const int t  = threadIdx.x;
    const int l  = t & 63;
    const int w  = t >> 6;
    const int s  = w >> 2;     // entity slot 0..1
    const int qr = w & 3;      // dim quarter 0..3
    const int b  = blockIdx.x;

    const float4* Q4 = (const float4*)Q;
    const float4* E4 = (const float4*)E;

    // ---- P1: stage Q transposed [g][query] (coalesced) ----
#pragma unroll
    for (int it = 0; it < 8; ++it) {
        const int f = t + TPB * it;                  // f = query*64 + g
        QT[(f & 63) * 65 + (f >> 6)] = Q4[f];
    }
    __syncthreads();

    // ---- reg-fill: lane l holds query l's quarter (16 float4, conflict-free reads) ----
    float4 qreg[16];
#pragma unroll
    for (int j = 0; j < 16; ++j) qreg[j] = QT[(qr * 16 + j) * 65 + l];

    double sqq = 0.0;                                // exact quarter sum
#pragma unroll
    for (int j = 0; j < 16; ++j) {
        float p0 = qreg[j].x + qreg[j].y;            // exact (24-bit)
        float p1 = qreg[j].z + qreg[j].w;
        sqq += (double)p0 + (double)p1;
    }
    __syncthreads();                                 // QT reads done -> P2 overlay

    double* SQd = (double*)SM;                       // [4][64]
    double* Cd  = (double*)(SM + 2048);              // [2][10][4][64]
    if (s == 0) SQd[qr * 64 + l] = sqq;

    // ---- entity loop: pure-register min/accumulate ----
    const int ebase = b * EPB + s * EPS;
#pragma unroll 1
    for (int i = 0; i < EPS; ++i) {
        const float4* ep = E4 + (size_t)(ebase + i) * 64 + qr * 16;  // wave-uniform
        double acc0 = 0.0, acc1 = 0.0;
        DIMS16(0) DIMS16(1) DIMS16(2) DIMS16(3)
        Cd[((s * EPS + i) * 4 + qr) * 64 + l] = acc0 + acc1;
    }
    __syncthreads();

    // ---- combine quarters + dual insertion-select ((qr==0) waves) ----
    double tv[K]; int ti[K]; double bv[K]; int bi[K];
    if (qr == 0) {
        const double Sq = SQd[l] + SQd[64 + l] + SQd[128 + l] + SQd[192 + l];
#pragma unroll
        for (int o = 0; o < K; ++o) {
            tv[o] = -INFINITY; ti[o] = INT_MAX;
            bv[o] = -INFINITY; bi[o] = INT_MAX;      // bv holds negated values
        }
#pragma unroll
        for (int i = 0; i < EPS; ++i) {
            const int ent = ebase + i;
            const int ci = (s * EPS + i) * 4;
            double inter = (Cd[(ci + 0) * 64 + l] + Cd[(ci + 1) * 64 + l])
                         + (Cd[(ci + 2) * 64 + l] + Cd[(ci + 3) * 64 + l]);
            double uni = Sq + Se[ent] - inter;       // min+max == q+e exactly
            double jac = inter / uni;                // exact operands -> IEEE-deterministic

            if (better_top(jac, ent, tv[K - 1], ti[K - 1])) {
                tv[K - 1] = jac; ti[K - 1] = ent;
#pragma unroll
                for (int ss = K - 1; ss > 0; --ss) {
                    if (better_top(tv[ss], ti[ss], tv[ss - 1], ti[ss - 1])) {
                        double tm = tv[ss]; tv[ss] = tv[ss - 1]; tv[ss - 1] = tm;
                        int    ii = ti[ss]; ti[ss] = ti[ss - 1]; ti[ss - 1] = ii;
                    }
                }
            }
            double nj = -jac;
            if (better_top(nj, ent, bv[K - 1], bi[K - 1])) {
                bv[K - 1] = nj; bi[K - 1] = ent;
#pragma unroll
                for (int ss = K - 1; ss > 0; --ss) {
                    if (better_top(bv[ss], bi[ss], bv[ss - 1], bi[ss - 1])) {
                        double tm = bv[ss]; bv[ss] = bv[ss - 1]; bv[ss - 1] = tm;
                        int    ii = bi[ss]; bi[ss] = bi[ss - 1]; bi[ss - 1] = ii;
                    }
                }
            }
        }
    }
    __syncthreads();                                 // Cd/SQd reads done -> P3 overlay

    double*         Mv = (double*)SM;                // [128*SLOT]
    unsigned short* Mi = (unsigned short*)(SM + 11264);

    // TOP: 2 slot-lists per query -> 1 list per block
    if (qr == 0) {
#pragma unroll
        for (int o = 0; o < K; ++o) { Mv[(s * 64 + l) * SLOT + o] = tv[o]; Mi[(s * 64 + l) * SLOT + o] = (unsigned short)ti[o]; }
    }
    __syncthreads();
    if (w == 0) {
        merge_slots16(Mv, Mi, l, 64 + l);
        const size_t off = ((size_t)b * NQ + l) * K;    // layout [list][query][K]
#pragma unroll
        for (int o = 0; o < K; ++o) { pvT[off + o] = Mv[l * SLOT + o]; piT[off + o] = Mi[l * SLOT + o]; }
    }
    __syncthreads();

    // BOT (negated values, same comparator)
    if (qr == 0) {
#pragma unroll
        for (int o = 0; o < K; ++o) { Mv[(s * 64 + l) * SLOT + o] = bv[o]; Mi[(s * 64 + l) * SLOT + o] = (unsigned short)bi[o]; }
    }
    __syncthreads();
    if (w == 0) {
        merge_slots16(Mv, Mi, l, 64 + l);
        const size_t off = ((size_t)b * NQ + l) * K;
#pragma unroll
        for (int o = 0; o < K; ++o) { pvB[off + o] = Mv[l * SLOT + o]; piB[off + o] = Mi[l * SLOT + o]; }
    }
}

// ---------------- kernel 2: fold 500->256 lists, then 10-round max-extraction ----------------
// grid = 128: block -> query q = bid>>1, dir = bid&1. BOT values arrive pre-negated.
__global__ __launch_bounds__(256) void final_extract(
        const double* __restrict__ pvT, const double* __restrict__ pvB,
        const unsigned short* __restrict__ piT, const unsigned short* __restrict__ piB,
        int* __restrict__ out) {
    __shared__ double Lv[256 * K];      // 20480 B
    __shared__ int    Li[256 * K];      // 10240 B
    __shared__ double Wv[4];
    __shared__ int    Wi[4], Wo[4];
    __shared__ int    res[K];

    const int bid = blockIdx.x;
    const int q   = bid >> 1;
    const bool top = (bid & 1) == 0;
    const int t   = threadIdx.x;
    const int l   = t & 63;
    const int w   = t >> 6;

    const double*         V = top ? pvT : pvB;
    const unsigned short* I = top ? piT : piB;

    // load list t ([list][query][K] layout), fold list t+256 if present
#pragma unroll
    for (int o = 0; o < K; ++o) {
        Lv[t * K + o] = V[((size_t)t * NQ + q) * K + o];
        Li[t * K + o] = (int)I[((size_t)t * NQ + q) * K + o];
    }
    for (int src = t + 256; src < NBLK; src += 256) {
        double ov[K]; int oi[K];
        int a = 0, bb = 0;
        const size_t sb = ((size_t)src * NQ + q) * K;
#pragma unroll
        for (int o = 0; o < K; ++o) {
            double va = Lv[t * K + a]; int ia = Li[t * K + a];
            double vb = V[sb + bb];    int ib = (int)I[sb + bb];
            bool pick = better_top(va, ia, vb, ib);
            ov[o] = pick ? va : vb; oi[o] = pick ? ia : ib;
            if (pick) ++a; else ++bb;
        }
#pragma unroll
        for (int o = 0; o < K; ++o) { Lv[t * K + o] = ov[o]; Li[t * K + o] = oi[o]; }
    }
    __syncthreads();

    // per-thread head; each of the 256 slots is sorted best-first
    int h = 0;
    double hv = Lv[t * K];
    int    hi = Li[t * K];

    for (int r = 0; r < K; ++r) {
        double v = hv; int idx = hi; int own = t;
#pragma unroll
        for (int m = 1; m < 64; m <<= 1) {
            double ov = __shfl_xor(v, m, 64);
            int    oi = __shfl_xor(idx, m, 64);
            int    oo = __shfl_xor(own, m, 64);
            if (better_top(ov, oi, v, idx)) { v = ov; idx = oi; own = oo; }
        }
        if (l == 0) { Wv[w] = v; Wi[w] = idx; Wo[w] = own; }
        __syncthreads();
        double gv = Wv[0]; int gi = Wi[0], go = Wo[0];
#pragma unroll
        for (int ww = 1; ww < 4; ++ww)
            if (better_top(Wv[ww], Wi[ww], gv, gi)) { gv = Wv[ww]; gi = Wi[ww]; go = Wo[ww]; }
        if (t == go) {          // winner advances its head (LDS dynamic index: fine)
            ++h;
            bool ok = h < K;
            hv = ok ? Lv[t * K + h] : -INFINITY;
            hi = ok ? Li[t * K + h] : INT_MAX;
        }
        if (t == 0) res[r] = gi;
        __syncthreads();
    }

    if (t < K) out[(top ? 0 : NQ * K) + q * K + t] = res[t];
}

extern "C" void kernel_launch(void* const* d_in, const int* in_sizes, int n_in,
                              void* d_out, int out_size, void* d_ws, size_t ws_size,
                              hipStream_t stream) {
    const float* Q = (const float*)d_in[0];   // [64, 256]
    const float* E = (const float*)d_in[1];   // [10000, 256]
    int* out = (int*)d_out;                   // 640 top idx + 640 bot idx

    // workspace: Se(f64) + list-major partials (6.48 MB)
    char* ws = (char*)d_ws;
    double*         Se  = (double*)(ws);                 // 81,920 (padded)
    double*         pvT = (double*)(ws + 81920);         // 500*64*10*8 = 2,560,000
    double*         pvB = (double*)(ws + 2641920);       // 2,560,000 (negated)
    unsigned short* piT = (unsigned short*)(ws + 5201920);  // 640,000
    unsigned short* piB = (unsigned short*)(ws + 5841920);  // 640,000

    hipLaunchKernelGGL(ent_sums, dim3(NE / 4), dim3(256), 0, stream, E, Se);
    hipLaunchKernelGGL(jac_part, dim3(NBLK), dim3(TPB), 0, stream,
                       Q, E, Se, pvT, pvB, piT, piB);
    hipLaunchKernelGGL(final_extract, dim3(NQ * 2), dim3(256), 0, stream,
                       pvT, pvB, piT, piB, out);
}